// Round 1
// baseline (428.808 us; speedup 1.0000x reference)
//
#include <hip/hip_runtime.h>

// y[b,:] = x[b,:] - (2 * dot(x[b],v) / dot(v,v)) * v
// D = 128 floats per row; 32 lanes * float4 = one row.
__global__ __launch_bounds__(256) void hh_kernel(const float* __restrict__ x,
                                                 const float* __restrict__ v,
                                                 float* __restrict__ y,
                                                 int nrows) {
    const int tid = threadIdx.x;
    const int c = tid & 31;  // column chunk within the row (32 x float4 = 128 floats)

    // v fragment for this lane (v is 128 floats, L1/L2-resident)
    const float4 v4 = reinterpret_cast<const float4*>(v)[c];

    // ||v||^2 via reduce within the 32-lane row group (masks 1..16 stay in-group)
    float p = v4.x * v4.x + v4.y * v4.y + v4.z * v4.z + v4.w * v4.w;
#pragma unroll
    for (int m = 16; m >= 1; m >>= 1) p += __shfl_xor(p, m, 64);
    const float scale = 2.0f / p;

    const int rows_per_block = blockDim.x >> 5;                 // 8
    const int rgroup = tid >> 5;
    const int row_stride = gridDim.x * rows_per_block;

    for (int row = blockIdx.x * rows_per_block + rgroup; row < nrows; row += row_stride) {
        const float4 x4 = reinterpret_cast<const float4*>(x + (size_t)row * 128)[c];
        float d = x4.x * v4.x + x4.y * v4.y + x4.z * v4.z + x4.w * v4.w;
#pragma unroll
        for (int m = 16; m >= 1; m >>= 1) d += __shfl_xor(d, m, 64);
        const float a = scale * d;
        float4 o;
        o.x = x4.x - a * v4.x;
        o.y = x4.y - a * v4.y;
        o.z = x4.z - a * v4.z;
        o.w = x4.w - a * v4.w;
        reinterpret_cast<float4*>(y + (size_t)row * 128)[c] = o;
    }

    // second tuple output: the scalar 0, stored after y
    if (blockIdx.x == 0 && tid == 0) y[(size_t)nrows * 128] = 0.0f;
}

extern "C" void kernel_launch(void* const* d_in, const int* in_sizes, int n_in,
                              void* d_out, int out_size, void* d_ws, size_t ws_size,
                              hipStream_t stream) {
    const float* x = (const float*)d_in[0];
    const float* v = (const float*)d_in[1];
    float* y = (float*)d_out;
    const int nrows = in_sizes[0] / 128;  // B = 2097152

    const int block = 256;
    const int rows_per_block = block / 32;
    int grid = (nrows + rows_per_block - 1) / rows_per_block;
    if (grid > 2048) grid = 2048;  // grid-stride the rest (G11)

    hh_kernel<<<grid, block, 0, stream>>>(x, v, y, nrows);
}

// Round 3
// 383.983 us; speedup vs baseline: 1.1167x; 1.1167x over previous
//
#include <hip/hip_runtime.h>

typedef float f32x4 __attribute__((ext_vector_type(4)));

// y[b,:] = x[b,:] - (2 * dot(x[b],v) / ||v||^2) * v
// D = 128 floats/row; 32 lanes x float4 = one row. 4 rows per group-iteration.
__global__ __launch_bounds__(256) void hh_kernel(const float* __restrict__ x,
                                                 const float* __restrict__ v,
                                                 float* __restrict__ y,
                                                 int nrows) {
    const int tid = threadIdx.x;
    const int c = tid & 31;     // float4 index within the row
    const int rg = tid >> 5;    // row-group within block (0..7)

    const f32x4 v4 = reinterpret_cast<const f32x4*>(v)[c];

    // ||v||^2 : butterfly within the 32-lane group (masks <=16 stay in-group)
    float p = v4.x * v4.x + v4.y * v4.y + v4.z * v4.z + v4.w * v4.w;
#pragma unroll
    for (int m = 16; m >= 1; m >>= 1) p += __shfl_xor(p, m, 64);
    const float scale = 2.0f / p;

    const int n_groups = gridDim.x * 8;
    const int n_chunks = nrows >> 2;  // chunks of 4 consecutive rows

    for (int chunk = blockIdx.x * 8 + rg; chunk < n_chunks; chunk += n_groups) {
        const f32x4* xp = reinterpret_cast<const f32x4*>(x + (size_t)chunk * 512) + c;
        f32x4* yp = reinterpret_cast<f32x4*>(y + (size_t)chunk * 512) + c;

        const f32x4 a0 = __builtin_nontemporal_load(xp);
        const f32x4 a1 = __builtin_nontemporal_load(xp + 32);
        const f32x4 a2 = __builtin_nontemporal_load(xp + 64);
        const f32x4 a3 = __builtin_nontemporal_load(xp + 96);

        float d0 = a0.x * v4.x + a0.y * v4.y + a0.z * v4.z + a0.w * v4.w;
        float d1 = a1.x * v4.x + a1.y * v4.y + a1.z * v4.z + a1.w * v4.w;
        float d2 = a2.x * v4.x + a2.y * v4.y + a2.z * v4.z + a2.w * v4.w;
        float d3 = a3.x * v4.x + a3.y * v4.y + a3.z * v4.z + a3.w * v4.w;
#pragma unroll
        for (int m = 16; m >= 1; m >>= 1) {
            d0 += __shfl_xor(d0, m, 64);
            d1 += __shfl_xor(d1, m, 64);
            d2 += __shfl_xor(d2, m, 64);
            d3 += __shfl_xor(d3, m, 64);
        }
        const float s0 = scale * d0, s1 = scale * d1, s2 = scale * d2, s3 = scale * d3;

        f32x4 o0, o1, o2, o3;
        o0.x = a0.x - s0 * v4.x; o0.y = a0.y - s0 * v4.y; o0.z = a0.z - s0 * v4.z; o0.w = a0.w - s0 * v4.w;
        o1.x = a1.x - s1 * v4.x; o1.y = a1.y - s1 * v4.y; o1.z = a1.z - s1 * v4.z; o1.w = a1.w - s1 * v4.w;
        o2.x = a2.x - s2 * v4.x; o2.y = a2.y - s2 * v4.y; o2.z = a2.z - s2 * v4.z; o2.w = a2.w - s2 * v4.w;
        o3.x = a3.x - s3 * v4.x; o3.y = a3.y - s3 * v4.y; o3.z = a3.z - s3 * v4.z; o3.w = a3.w - s3 * v4.w;

        __builtin_nontemporal_store(o0, yp);
        __builtin_nontemporal_store(o1, yp + 32);
        __builtin_nontemporal_store(o2, yp + 64);
        __builtin_nontemporal_store(o3, yp + 96);
    }

    // tail rows if nrows % 4 != 0 (not hit for B = 2^21, kept for safety)
    if (blockIdx.x == 0 && rg == 0) {
        for (int row = n_chunks << 2; row < nrows; ++row) {
            const f32x4 a = reinterpret_cast<const f32x4*>(x + (size_t)row * 128)[c];
            float d = a.x * v4.x + a.y * v4.y + a.z * v4.z + a.w * v4.w;
#pragma unroll
            for (int m = 16; m >= 1; m >>= 1) d += __shfl_xor(d, m, 64);
            const float s = scale * d;
            f32x4 o;
            o.x = a.x - s * v4.x; o.y = a.y - s * v4.y; o.z = a.z - s * v4.z; o.w = a.w - s * v4.w;
            reinterpret_cast<f32x4*>(y + (size_t)row * 128)[c] = o;
        }
    }

    // second tuple output: scalar 0 after y
    if (blockIdx.x == 0 && tid == 0) y[(size_t)nrows * 128] = 0.0f;
}

extern "C" void kernel_launch(void* const* d_in, const int* in_sizes, int n_in,
                              void* d_out, int out_size, void* d_ws, size_t ws_size,
                              hipStream_t stream) {
    const float* x = (const float*)d_in[0];
    const float* v = (const float*)d_in[1];
    float* y = (float*)d_out;
    const int nrows = in_sizes[0] / 128;

    const int block = 256;
    const int groups_per_block = block / 32;
    const int n_chunks = nrows / 4;
    int grid = (n_chunks + groups_per_block - 1) / groups_per_block;
    if (grid > 2048) grid = 2048;
    if (grid < 1) grid = 1;

    hh_kernel<<<grid, block, 0, stream>>>(x, v, y, nrows);
}